// Round 3
// baseline (366.159 us; speedup 1.0000x reference)
//
#include <hip/hip_runtime.h>
#include <hip/hip_bf16.h>

// Problem constants (from reference)
constexpr int NN = 90000;   // total nodes
constexpr int NP = 60000;   // paper nodes
constexpr int NM = 30000;   // mesh nodes
constexpr int ET = 2000000; // train edges
constexpr int ED = 400000;  // decode edges (each of pos/neg)
constexpr int TWO_NN = 2 * NN;

// Binned CSR build parameters.
// R19: edge lists padded to multiple of 8 with zero-row (src=NN) sentinels =>
// branch-free 8-wide gather pipeline. BKT_CAP raised for pad slack:
// padded bucket mean 7475, sigma ~91 -> 8448 = mean + 10.7 sigma.
constexpr int BKT_SH  = 9;                           // 512 keys per bucket
constexpr int NB_BKT  = (TWO_NN + 511) >> BKT_SH;    // 352 buckets
constexpr int BKT_CAP = 8448;
constexpr int TILE    = 2048;                        // edges per binning tile
constexpr int N_TILES = (ET + TILE - 1) / TILE;      // 977

__device__ __forceinline__ float bflo(unsigned int u) {
    union { unsigned int i; float f; } c;
    c.i = u << 16;
    return c.f;
}
__device__ __forceinline__ float bfhi(unsigned int u) {
    union { unsigned int i; float f; } c;
    c.i = u & 0xffff0000u;
    return c.f;
}
__device__ __forceinline__ unsigned short f2bf(float f) {
    union { float f; unsigned int i; } c;
    c.f = f;
    unsigned int x = c.i;
    return (unsigned short)((x + 0x7FFFu + ((x >> 16) & 1u)) >> 16);
}

// ---------------------------------------------------------------------------
// Init: gcur cursors + int32/int64 dtype flag + zero-row sentinels.
// Row NN must be zero in every layout it is read in:
//   xbfA as DIN=16 input (layer 1), xbfA/xbfB as DIN=32 inputs (layers 2-4).
__global__ void init_kernel(const int* __restrict__ tei, int* __restrict__ gcur,
                            int* __restrict__ dflag,
                            unsigned short* __restrict__ xbfA,
                            unsigned short* __restrict__ xbfB) {
    int b = blockIdx.x * blockDim.x + threadIdx.x;
    if (b < NB_BKT) gcur[b] = b * BKT_CAP;
    if (b < 32) {
        xbfA[(size_t)NN * 32 + b] = 0;
        xbfB[(size_t)NN * 32 + b] = 0;
        if (b < 16) xbfA[(size_t)NN * 16 + b] = 0;
    }
    if (b == 0) {
        int allzero = 1;
        for (int i = 0; i < 16; i++)
            if (tei[2 * i + 1] != 0) allzero = 0;
        dflag[0] = allzero; // 1 => int64 => index shift 1
    }
}

// ---------------------------------------------------------------------------
// Pass A: bin edges into per-bucket pair arrays with line-dense writes.
__global__ void __launch_bounds__(256) binA_kernel(
        const int* __restrict__ ei, const int* __restrict__ et,
        const int* __restrict__ dflag, int* __restrict__ gcur,
        int2* __restrict__ pairs) {
    __shared__ int histw[4][NB_BKT];
    __shared__ int wbase[4][NB_BKT];
    __shared__ int tot[NB_BKT];
    __shared__ int excl[NB_BKT];
    __shared__ int gbase[NB_BKT];
    __shared__ int scn[256];
    __shared__ int2 tbuf[TILE];
    int t = threadIdx.x;
    int w = t >> 6; // wave id (4 waves of 64)
    int tile0 = blockIdx.x * TILE;
    int tcount = ET - tile0;
    if (tcount > TILE) tcount = TILE;
    for (int i = t; i < 4 * NB_BKT; i += 256) ((int*)histw)[i] = 0;
    __syncthreads();
    int sft = dflag[0];
    int myk[8], mys[8];
#pragma unroll
    for (int q = 0; q < 8; q++) {
        int li = q * 256 + t;
        myk[q] = -1;
        if (li < tcount) {
            int e = tile0 + li;
            int s = ei[(size_t)e << sft];
            int d = ei[(size_t)(ET + e) << sft];
            int r = et[(size_t)e << sft];
            int key = r * NN + d;
            myk[q] = key;
            mys[q] = s;
            atomicAdd(&histw[w][key >> BKT_SH], 1);
        }
    }
    __syncthreads();
    // combine per-wave histograms -> tot, per-wave placement offsets
    for (int i = t; i < NB_BKT; i += 256) {
        int h0 = histw[0][i], h1 = histw[1][i], h2 = histw[2][i], h3 = histw[3][i];
        wbase[0][i] = 0;
        wbase[1][i] = h0;
        wbase[2][i] = h0 + h1;
        wbase[3][i] = h0 + h1 + h2;
        tot[i] = h0 + h1 + h2 + h3;
    }
    __syncthreads();
    // exclusive scan of tot over 352 bins (2 bins per thread, t<176)
    int v0 = (t < NB_BKT / 2) ? tot[2 * t] : 0;
    int v1 = (t < NB_BKT / 2) ? tot[2 * t + 1] : 0;
    int s = v0 + v1;
    scn[t] = s;
    __syncthreads();
    for (int st = 1; st < 256; st <<= 1) {
        int u = (t >= st) ? scn[t - st] : 0;
        __syncthreads();
        scn[t] += u;
        __syncthreads();
    }
    int base = scn[t] - s;
    if (t < NB_BKT / 2) {
        excl[2 * t] = base;
        excl[2 * t + 1] = base + v0;
    }
    __syncthreads();
    // finalize per-wave bases; reset histw for reuse as placement cursors
    for (int i = t; i < NB_BKT; i += 256) {
        int e0 = excl[i];
        wbase[0][i] += e0;
        wbase[1][i] += e0;
        wbase[2][i] += e0;
        wbase[3][i] += e0;
        histw[0][i] = 0; histw[1][i] = 0; histw[2][i] = 0; histw[3][i] = 0;
    }
    __syncthreads();
    // place into LDS tile buffer (bucket-contiguous; per-wave cursor)
#pragma unroll
    for (int q = 0; q < 8; q++) {
        if (myk[q] >= 0) {
            int b = myk[q] >> BKT_SH;
            int p = wbase[w][b] + atomicAdd(&histw[w][b], 1);
            tbuf[p] = make_int2(myk[q], mys[q]);
        }
    }
    __syncthreads();
    // reserve global runs
    for (int i = t; i < NB_BKT; i += 256)
        if (tot[i] > 0) gbase[i] = atomicAdd(&gcur[i], tot[i]);
    __syncthreads();
    // flush: consecutive i -> mostly consecutive global positions
    for (int i = t; i < tcount; i += 256) {
        int2 p = tbuf[i];
        int b = p.x >> BKT_SH;
        int gpos = gbase[b] + (i - excl[b]);
        int cap = (b + 1) * BKT_CAP - 1;
        pairs[gpos < cap ? gpos : cap] = p;
    }
}

// ---------------------------------------------------------------------------
// Pass B (merged hist+place): per-bucket key histogram + block-local scan ->
// off/endo/inv, then place into padded CSR. 352 blocks (512 keys each).
// R19: per-key slot runs rounded up to multiple of 8; pad slots get src=NN
// (zero row). endo = padded end; inv uses true count.
__global__ void __launch_bounds__(256) histplace_kernel(
        const int* __restrict__ gcur, const int2* __restrict__ pairs,
        int* __restrict__ off, int* __restrict__ endo, float* __restrict__ inv,
        int* __restrict__ csr) {
    __shared__ int kh[512];
    __shared__ int scn[256];
    int b = blockIdx.x;
    int t = threadIdx.x;
    int beg = b * BKT_CAP, end = gcur[b];
    for (int i = t; i < 512; i += 256) kh[i] = 0;
    __syncthreads();
    for (int i = beg + t; i < end; i += 256)
        atomicAdd(&kh[pairs[i].x & 511], 1);
    __syncthreads();
    int v[2];
    int s = 0;
#pragma unroll
    for (int q = 0; q < 2; q++) {
        v[q] = kh[t * 2 + q];
        s += (v[q] + 7) & ~7; // padded width
    }
    scn[t] = s;
    __syncthreads();
    for (int st = 1; st < 256; st <<= 1) {
        int u = (t >= st) ? scn[t - st] : 0;
        __syncthreads();
        scn[t] += u;
        __syncthreads();
    }
    int run = beg + scn[t] - s;
    int kbase = b << BKT_SH;
    int kc[2];
#pragma unroll
    for (int q = 0; q < 2; q++) {
        int key = kbase + t * 2 + q;
        int vp = (v[q] + 7) & ~7;
        if (key < TWO_NN) {
            off[key] = run;
            endo[key] = run + vp;
            inv[key] = 1.0f / (float)(v[q] > 1 ? v[q] : 1);
            for (int i = run + v[q]; i < run + vp; i++) csr[i] = NN; // pad
        }
        kc[q] = run;
        run += vp;
    }
    __syncthreads();
#pragma unroll
    for (int q = 0; q < 2; q++) kh[t * 2 + q] = kc[q];
    __syncthreads();
    for (int i = beg + t; i < end; i += 256) {
        int2 p = pairs[i];
        int pos = atomicAdd(&kh[p.x & 511], 1);
        csr[pos] = p.y;
    }
}

// ---------------------------------------------------------------------------
// Fused input embed (paper+mesh): writes bf16 activations only.
__global__ void __launch_bounds__(256) embed2_kernel(
        const float* __restrict__ Xp, const float* __restrict__ Xm,
        const float* __restrict__ Wp, const float* __restrict__ bp,
        const float* __restrict__ Wm, const float* __restrict__ bm,
        unsigned short* __restrict__ outbf) {
    __shared__ float Wl[4096 + 32];
    for (int i = threadIdx.x; i < 2048; i += 256) {
        Wl[i] = Wp[i];
        Wl[2048 + i] = Wm[i];
    }
    if (threadIdx.x < 16) {
        Wl[4096 + threadIdx.x] = bp[threadIdx.x];
        Wl[4112 + threadIdx.x] = bm[threadIdx.x];
    }
    __syncthreads();
    int n = blockIdx.x * 256 + threadIdx.x;
    if (n >= NN) return;
    const float* X;
    const float* Ws;
    const float* Bs;
    if (n < NP) { X = Xp + (size_t)n * 128; Ws = Wl; Bs = Wl + 4096; }
    else        { X = Xm + (size_t)(n - NP) * 128; Ws = Wl + 2048; Bs = Wl + 4112; }
    float acc[16];
#pragma unroll
    for (int j = 0; j < 16; j++) acc[j] = Bs[j];
    const float4* row = (const float4*)X;
    for (int k4 = 0; k4 < 32; k4++) {
        float4 xv = row[k4];
        int k = k4 * 4;
#pragma unroll
        for (int j = 0; j < 16; j++) {
            float a = acc[j];
            a = fmaf(xv.x, Ws[(k + 0) * 16 + j], a);
            a = fmaf(xv.y, Ws[(k + 1) * 16 + j], a);
            a = fmaf(xv.z, Ws[(k + 2) * 16 + j], a);
            a = fmaf(xv.w, Ws[(k + 3) * 16 + j], a);
            acc[j] = a;
        }
    }
    ushort4* ob = (ushort4*)(outbf + (size_t)n * 16);
#pragma unroll
    for (int q = 0; q < 4; q++) {
        ushort4 ub;
        ub.x = f2bf(acc[4 * q]);     ub.y = f2bf(acc[4 * q + 1]);
        ub.z = f2bf(acc[4 * q + 2]); ub.w = f2bf(acc[4 * q + 3]);
        ob[q] = ub;
    }
}

// ---------------------------------------------------------------------------
// All 4 layers' weight prep in ONE launch: block l handles layer l.
// Wbuf4 layout per layer (stride 3200): [W0 | W1 | root | bias]
__global__ void prep_all_kernel(
        const float* __restrict__ ba0, const float* __restrict__ co0,
        const float* __restrict__ ro0, const float* __restrict__ bi0,
        const float* __restrict__ ba1, const float* __restrict__ co1,
        const float* __restrict__ ro1, const float* __restrict__ bi1,
        const float* __restrict__ ba2, const float* __restrict__ co2,
        const float* __restrict__ ro2, const float* __restrict__ bi2,
        const float* __restrict__ ba3, const float* __restrict__ co3,
        const float* __restrict__ ro3, const float* __restrict__ bi3,
        float* __restrict__ Wbuf4) {
    int l = blockIdx.x;
    const float* bases; const float* comp; const float* root; const float* bias;
    if (l == 0)      { bases = ba0; comp = co0; root = ro0; bias = bi0; }
    else if (l == 1) { bases = ba1; comp = co1; root = ro1; bias = bi1; }
    else if (l == 2) { bases = ba2; comp = co2; root = ro2; bias = bi2; }
    else             { bases = ba3; comp = co3; root = ro3; bias = bi3; }
    int din = (l == 0) ? 16 : 32;
    int dout = (l == 3) ? 16 : 32;
    int sz = din * dout;
    float* W = Wbuf4 + l * 3200;
    for (int i = threadIdx.x; i < sz; i += 256) {
        float b0 = bases[i];
        float b1 = bases[sz + i];
        float b2 = bases[2 * sz + i];
        float b3 = bases[3 * sz + i];
        for (int r = 0; r < 2; r++) {
            W[r * sz + i] = comp[r * 4 + 0] * b0 + comp[r * 4 + 1] * b1 +
                            comp[r * 4 + 2] * b2 + comp[r * 4 + 3] * b3;
        }
        W[2 * sz + i] = root[i];
    }
    if (threadIdx.x < dout) W[3 * sz + threadIdx.x] = bias[threadIdx.x];
}

// Accumulate one uint4 (8 bf16) into an 8-float accumulator bank.
#define ACCU(u, a)                                   \
    a[0] += bflo(u.x); a[1] += bfhi(u.x);            \
    a[2] += bflo(u.y); a[3] += bfhi(u.y);            \
    a[4] += bflo(u.z); a[5] += bfhi(u.z);            \
    a[6] += bflo(u.w); a[7] += bfhi(u.w);

// ---------------------------------------------------------------------------
// Fused RGCN layer, bf16-only activations.
// R19: CSR padded to multiples of 8 (sentinel src=NN -> zero row, L1-hot) =>
// branch-free 8-wide software-pipelined gather: 8 outstanding 16B x-loads,
// next batch's csr indices prefetched during flight. No remainder path
// (R18's 1-wide remainder cost up to 3 serial latency round-trips per key).
template <int DIN, int DOUT, int RELU>
__global__ void __launch_bounds__(256) layer_kernel(
        const int* __restrict__ off, const int* __restrict__ endo,
        const int* __restrict__ csr,
        const unsigned short* __restrict__ xbf_in,
        const float* __restrict__ inv, const float* __restrict__ Wbuf,
        unsigned short* __restrict__ xbf_out) {
    constexpr int SZ = DIN * DOUT;
    constexpr int QL = DIN / 8;       // gather lanes per (node, rel): 16 B each
    constexpr int TPN = 2 * QL;       // phase-1 threads per node
    constexpr int NPB = 256 / TPN;    // nodes per block
    constexpr int AGST = 2 * DIN + 4; // agg LDS row stride (floats)
    constexpr int XSST = DIN + 8;     // xs LDS row stride (ushorts, 16B-mult)
    __shared__ float Wl[3 * SZ + DOUT];
    __shared__ float agg[NPB * AGST];
    __shared__ unsigned short xsu[NPB * XSST];
    for (int i = threadIdx.x; i < 3 * SZ + DOUT; i += 256) Wl[i] = Wbuf[i];
    int t = threadIdx.x;
    int ln = t / TPN;
    int rl = t % TPN;
    int r = rl / QL;
    int lane = rl % QL;
    int d = blockIdx.x * NPB + ln;
    if (d < NN) {
        if (r == 0) {
            uint4 u = *(const uint4*)(xbf_in + (size_t)d * DIN + lane * 8);
            *(uint4*)&xsu[ln * XSST + lane * 8] = u; // raw bf16, unpack in ph2
        }
        int key = r * NN + d;
        int b = off[key];
        int e = endo[key]; // padded: (e-b) % 8 == 0
        float a0[8] = {0, 0, 0, 0, 0, 0, 0, 0};
        float a1[8] = {0, 0, 0, 0, 0, 0, 0, 0};
        const unsigned short* hp = xbf_in + lane * 8;
        int k = b;
        if (k < e) {
            int s0 = csr[k], s1 = csr[k + 1], s2 = csr[k + 2], s3 = csr[k + 3];
            int s4 = csr[k + 4], s5 = csr[k + 5], s6 = csr[k + 6], s7 = csr[k + 7];
            k += 8;
            while (k < e) {
                uint4 u0 = *(const uint4*)(hp + (size_t)s0 * DIN);
                uint4 u1 = *(const uint4*)(hp + (size_t)s1 * DIN);
                uint4 u2 = *(const uint4*)(hp + (size_t)s2 * DIN);
                uint4 u3 = *(const uint4*)(hp + (size_t)s3 * DIN);
                uint4 u4 = *(const uint4*)(hp + (size_t)s4 * DIN);
                uint4 u5 = *(const uint4*)(hp + (size_t)s5 * DIN);
                uint4 u6 = *(const uint4*)(hp + (size_t)s6 * DIN);
                uint4 u7 = *(const uint4*)(hp + (size_t)s7 * DIN);
                s0 = csr[k]; s1 = csr[k + 1]; s2 = csr[k + 2]; s3 = csr[k + 3];
                s4 = csr[k + 4]; s5 = csr[k + 5]; s6 = csr[k + 6]; s7 = csr[k + 7];
                k += 8;
                ACCU(u0, a0) ACCU(u1, a1) ACCU(u2, a0) ACCU(u3, a1)
                ACCU(u4, a0) ACCU(u5, a1) ACCU(u6, a0) ACCU(u7, a1)
            }
            // drain last in-flight batch
            uint4 u0 = *(const uint4*)(hp + (size_t)s0 * DIN);
            uint4 u1 = *(const uint4*)(hp + (size_t)s1 * DIN);
            uint4 u2 = *(const uint4*)(hp + (size_t)s2 * DIN);
            uint4 u3 = *(const uint4*)(hp + (size_t)s3 * DIN);
            uint4 u4 = *(const uint4*)(hp + (size_t)s4 * DIN);
            uint4 u5 = *(const uint4*)(hp + (size_t)s5 * DIN);
            uint4 u6 = *(const uint4*)(hp + (size_t)s6 * DIN);
            uint4 u7 = *(const uint4*)(hp + (size_t)s7 * DIN);
            ACCU(u0, a0) ACCU(u1, a1) ACCU(u2, a0) ACCU(u3, a1)
            ACCU(u4, a0) ACCU(u5, a1) ACCU(u6, a0) ACCU(u7, a1)
        }
        float* ap = agg + ln * AGST + r * DIN + lane * 8;
        *(float4*)ap = make_float4(a0[0] + a1[0], a0[1] + a1[1],
                                   a0[2] + a1[2], a0[3] + a1[3]);
        *(float4*)(ap + 4) = make_float4(a0[4] + a1[4], a0[5] + a1[5],
                                         a0[6] + a1[6], a0[7] + a1[7]);
    }
    __syncthreads();
    constexpr int CPN = DOUT / 4;
    for (int tt = t; tt < NPB * CPN; tt += 256) {
        int ln2 = tt / CPN;
        int j0 = (tt % CPN) * 4;
        int d2 = blockIdx.x * NPB + ln2;
        if (d2 < NN) {
            float iv0 = inv[d2], iv1 = inv[NN + d2];
            float acc[4];
#pragma unroll
            for (int jj = 0; jj < 4; jj++) acc[jj] = Wl[3 * SZ + j0 + jj];
#pragma unroll
            for (int k2 = 0; k2 < DIN; k2 += 2) {
                unsigned up = *(const unsigned*)&xsu[ln2 * XSST + k2];
                float xv0 = bflo(up);
                float xv1 = bfhi(up);
                float m00 = agg[ln2 * AGST + k2] * iv0;
                float m10 = agg[ln2 * AGST + DIN + k2] * iv1;
                float m01 = agg[ln2 * AGST + k2 + 1] * iv0;
                float m11 = agg[ln2 * AGST + DIN + k2 + 1] * iv1;
                const float* w0a = &Wl[k2 * DOUT + j0];
                const float* w1a = &Wl[SZ + k2 * DOUT + j0];
                const float* wra = &Wl[2 * SZ + k2 * DOUT + j0];
#pragma unroll
                for (int jj = 0; jj < 4; jj++) {
                    acc[jj] = fmaf(xv0, wra[jj], acc[jj]);
                    acc[jj] = fmaf(m00, w0a[jj], acc[jj]);
                    acc[jj] = fmaf(m10, w1a[jj], acc[jj]);
                    acc[jj] = fmaf(xv1, wra[DOUT + jj], acc[jj]);
                    acc[jj] = fmaf(m01, w0a[DOUT + jj], acc[jj]);
                    acc[jj] = fmaf(m11, w1a[DOUT + jj], acc[jj]);
                }
            }
            if (RELU) {
#pragma unroll
                for (int jj = 0; jj < 4; jj++) acc[jj] = fmaxf(acc[jj], 0.0f);
            }
            ushort4 ub;
            ub.x = f2bf(acc[0]); ub.y = f2bf(acc[1]);
            ub.z = f2bf(acc[2]); ub.w = f2bf(acc[3]);
            *(ushort4*)(xbf_out + (size_t)d2 * DOUT + j0) = ub;
        }
    }
}

// ---------------------------------------------------------------------------
// Fused decode on bf16 z: out[i] = dot( z[s]@Wd_r + bd_r , z[d] ).
__global__ void __launch_bounds__(256) decode_fused_kernel(
        const unsigned short* __restrict__ zbf,
        const float* __restrict__ Wd0, const float* __restrict__ bd0,
        const float* __restrict__ Wd1, const float* __restrict__ bd1,
        const int* __restrict__ pei, const int* __restrict__ pet,
        const int* __restrict__ nei, const int* __restrict__ net_,
        float* __restrict__ out, const int* __restrict__ dflag) {
    __shared__ float W[2][256];
    __shared__ float B[2][16];
    for (int i = threadIdx.x; i < 256; i += 256) {
        W[0][i] = Wd0[i];
        W[1][i] = Wd1[i];
    }
    if (threadIdx.x < 16) {
        B[0][threadIdx.x] = bd0[threadIdx.x];
        B[1][threadIdx.x] = bd1[threadIdx.x];
    }
    __syncthreads();
    int i = blockIdx.x * 256 + threadIdx.x;
    if (i >= 2 * ED) return;
    int sft = dflag[0];
    const int* ei;
    const int* et;
    int e;
    if (i < ED) { ei = pei; et = pet; e = i; }
    else        { ei = nei; et = net_; e = i - ED; }
    int s = ei[(size_t)e << sft];
    int d = ei[(size_t)(ED + e) << sft];
    int r = et[(size_t)e << sft];
    float zs[16], zd[16];
    const uint4* sp = (const uint4*)(zbf + ((size_t)s << 4));
    const uint4* dp = (const uint4*)(zbf + ((size_t)d << 4));
#pragma unroll
    for (int h = 0; h < 2; h++) {
        uint4 us = sp[h];
        uint4 ud = dp[h];
        int o8 = h * 8;
        zs[o8 + 0] = bflo(us.x); zs[o8 + 1] = bfhi(us.x);
        zs[o8 + 2] = bflo(us.y); zs[o8 + 3] = bfhi(us.y);
        zs[o8 + 4] = bflo(us.z); zs[o8 + 5] = bfhi(us.z);
        zs[o8 + 6] = bflo(us.w); zs[o8 + 7] = bfhi(us.w);
        zd[o8 + 0] = bflo(ud.x); zd[o8 + 1] = bfhi(ud.x);
        zd[o8 + 2] = bflo(ud.y); zd[o8 + 3] = bfhi(ud.y);
        zd[o8 + 4] = bflo(ud.z); zd[o8 + 5] = bfhi(ud.z);
        zd[o8 + 6] = bflo(ud.w); zd[o8 + 7] = bfhi(ud.w);
    }
    const float* Wr = W[r];
    const float* Br = B[r];
    float acc = 0.0f;
#pragma unroll
    for (int j = 0; j < 16; j++) {
        float yj = Br[j];
#pragma unroll
        for (int k = 0; k < 16; k++) yj = fmaf(zs[k], Wr[k * 16 + j], yj);
        acc = fmaf(yj, zd[j], acc);
    }
    out[i] = acc;
}

// ---------------------------------------------------------------------------
extern "C" void kernel_launch(void* const* d_in, const int* in_sizes, int n_in,
                              void* d_out, int out_size, void* d_ws, size_t ws_size,
                              hipStream_t stream) {
    const float* x_paper = (const float*)d_in[0];
    const float* x_mesh  = (const float*)d_in[1];
    const int* tei  = (const int*)d_in[2];
    const int* tet  = (const int*)d_in[3];
    const int* pei  = (const int*)d_in[4];
    const int* pet  = (const int*)d_in[5];
    const int* nei  = (const int*)d_in[6];
    const int* net_ = (const int*)d_in[7];
    const float* Wp  = (const float*)d_in[8];
    const float* bp  = (const float*)d_in[9];
    const float* Wm  = (const float*)d_in[10];
    const float* bm  = (const float*)d_in[11];
    const float* Wd0 = (const float*)d_in[12];
    const float* bd0 = (const float*)d_in[13];
    const float* Wd1 = (const float*)d_in[14];
    const float* bd1 = (const float*)d_in[15];

    // Workspace carve-up (fp32/int32 elements) — ~60 MB total
    // x buffers hold NN+1 rows of up to 32 bf16 (row NN = zero sentinel).
    float* ws = (float*)d_ws;
    size_t o = 0;
    unsigned short* xbfA = (unsigned short*)(ws + o); o += (size_t)(NN + 1) * 16;
    unsigned short* xbfB = (unsigned short*)(ws + o); o += (size_t)(NN + 1) * 16;
    float* inv  = ws + o; o += (size_t)TWO_NN;
    int*   off  = (int*)(ws + o); o += (size_t)TWO_NN;
    int*   endo = (int*)(ws + o); o += (size_t)TWO_NN;
    int*   csr  = (int*)(ws + o); o += (size_t)NB_BKT * BKT_CAP; // padded (12 MB)
    int*   gcur = (int*)(ws + o); o += 512;
    int2*  pairs = (int2*)(ws + o); o += (size_t)2 * NB_BKT * BKT_CAP; // 24 MB
    float* Wbuf4 = ws + o; o += 4 * 3200;
    int*   dflag = (int*)(ws + o); o += 16;

    // 0. Init (gcur + dtype flag + zero-row sentinels)
    init_kernel<<<(NB_BKT + 255) / 256, 256, 0, stream>>>(tei, gcur, dflag,
                                                          xbfA, xbfB);

    // 1. Binned padded-bucket CSR build (once)
    binA_kernel<<<N_TILES, 256, 0, stream>>>(tei, tet, dflag, gcur, pairs);
    histplace_kernel<<<NB_BKT, 256, 0, stream>>>(gcur, pairs, off, endo, inv, csr);

    // 2. Fused embed -> xbfA (bf16 only)
    embed2_kernel<<<(NN + 255) / 256, 256, 0, stream>>>(
        x_paper, x_mesh, Wp, bp, Wm, bm, xbfA);

    // 3. All layer weights in one launch
    prep_all_kernel<<<4, 256, 0, stream>>>(
        (const float*)d_in[16], (const float*)d_in[17], (const float*)d_in[18], (const float*)d_in[19],
        (const float*)d_in[20], (const float*)d_in[21], (const float*)d_in[22], (const float*)d_in[23],
        (const float*)d_in[24], (const float*)d_in[25], (const float*)d_in[26], (const float*)d_in[27],
        (const float*)d_in[28], (const float*)d_in[29], (const float*)d_in[30], (const float*)d_in[31],
        Wbuf4);

    // 4. Four fused RGCN layers, bf16 activations throughout
    int blk16 = (NN + 63) / 64; // DIN=16: NPB=64
    int blk32 = (NN + 31) / 32; // DIN=32: NPB=32
    layer_kernel<16, 32, 1><<<blk16, 256, 0, stream>>>(
        off, endo, csr, xbfA, inv, Wbuf4 + 0 * 3200, xbfB);
    layer_kernel<32, 32, 1><<<blk32, 256, 0, stream>>>(
        off, endo, csr, xbfB, inv, Wbuf4 + 1 * 3200, xbfA);
    layer_kernel<32, 32, 1><<<blk32, 256, 0, stream>>>(
        off, endo, csr, xbfA, inv, Wbuf4 + 2 * 3200, xbfB);
    layer_kernel<32, 16, 0><<<blk32, 256, 0, stream>>>(
        off, endo, csr, xbfB, inv, Wbuf4 + 3 * 3200, xbfA);
    // z (bf16) = xbfA [NN,16]

    // 5. Fused decode on bf16 z
    decode_fused_kernel<<<(2 * ED + 255) / 256, 256, 0, stream>>>(
        xbfA, Wd0, bd0, Wd1, bd1, pei, pet, nei, net_, (float*)d_out, dflag);
}

// Round 4
// 353.220 us; speedup vs baseline: 1.0366x; 1.0366x over previous
//
#include <hip/hip_runtime.h>
#include <hip/hip_bf16.h>

// Problem constants (from reference)
constexpr int NN = 90000;   // total nodes
constexpr int NP = 60000;   // paper nodes
constexpr int NM = 30000;   // mesh nodes
constexpr int ET = 2000000; // train edges
constexpr int ED = 400000;  // decode edges (each of pos/neg)
constexpr int TWO_NN = 2 * NN;

// Binned CSR build parameters (R16: 512-key buckets for 2x block parallelism)
constexpr int BKT_SH  = 9;                           // 512 keys per bucket
constexpr int NB_BKT  = (TWO_NN + 511) >> BKT_SH;    // 352 buckets
constexpr int BKT_CAP = 6400;                        // mean 5683, +9.5 sigma
constexpr int TILE    = 2048;                        // edges per binning tile
constexpr int N_TILES = (ET + TILE - 1) / TILE;      // 977
// R20: src-range grouping of each key's edge list (group = src >> 14, 6 of 8
// used). Walk order becomes src-ascending by 1MB ranges -> gather working set
// at any instant ~1-2MB << 4MiB per-XCD L2 (vs 5.76MB random before).
constexpr int NG = 8;

__device__ __forceinline__ float bflo(unsigned int u) {
    union { unsigned int i; float f; } c;
    c.i = u << 16;
    return c.f;
}
__device__ __forceinline__ float bfhi(unsigned int u) {
    union { unsigned int i; float f; } c;
    c.i = u & 0xffff0000u;
    return c.f;
}
__device__ __forceinline__ unsigned short f2bf(float f) {
    union { float f; unsigned int i; } c;
    c.f = f;
    unsigned int x = c.i;
    return (unsigned short)((x + 0x7FFFu + ((x >> 16) & 1u)) >> 16);
}

// ---------------------------------------------------------------------------
// Init: gcur cursors + int32/int64 dtype flag (merged).
__global__ void init_kernel(const int* __restrict__ tei, int* __restrict__ gcur,
                            int* __restrict__ dflag) {
    int b = blockIdx.x * blockDim.x + threadIdx.x;
    if (b < NB_BKT) gcur[b] = b * BKT_CAP;
    if (b == 0) {
        int allzero = 1;
        for (int i = 0; i < 16; i++)
            if (tei[2 * i + 1] != 0) allzero = 0;
        dflag[0] = allzero; // 1 => int64 => index shift 1
    }
}

// ---------------------------------------------------------------------------
// Pass A: bin edges into per-bucket pair arrays with line-dense writes.
__global__ void __launch_bounds__(256) binA_kernel(
        const int* __restrict__ ei, const int* __restrict__ et,
        const int* __restrict__ dflag, int* __restrict__ gcur,
        int2* __restrict__ pairs) {
    __shared__ int histw[4][NB_BKT];
    __shared__ int wbase[4][NB_BKT];
    __shared__ int tot[NB_BKT];
    __shared__ int excl[NB_BKT];
    __shared__ int gbase[NB_BKT];
    __shared__ int scn[256];
    __shared__ int2 tbuf[TILE];
    int t = threadIdx.x;
    int w = t >> 6; // wave id (4 waves of 64)
    int tile0 = blockIdx.x * TILE;
    int tcount = ET - tile0;
    if (tcount > TILE) tcount = TILE;
    for (int i = t; i < 4 * NB_BKT; i += 256) ((int*)histw)[i] = 0;
    __syncthreads();
    int sft = dflag[0];
    int myk[8], mys[8];
#pragma unroll
    for (int q = 0; q < 8; q++) {
        int li = q * 256 + t;
        myk[q] = -1;
        if (li < tcount) {
            int e = tile0 + li;
            int s = ei[(size_t)e << sft];
            int d = ei[(size_t)(ET + e) << sft];
            int r = et[(size_t)e << sft];
            int key = r * NN + d;
            myk[q] = key;
            mys[q] = s;
            atomicAdd(&histw[w][key >> BKT_SH], 1);
        }
    }
    __syncthreads();
    // combine per-wave histograms -> tot, per-wave placement offsets
    for (int i = t; i < NB_BKT; i += 256) {
        int h0 = histw[0][i], h1 = histw[1][i], h2 = histw[2][i], h3 = histw[3][i];
        wbase[0][i] = 0;
        wbase[1][i] = h0;
        wbase[2][i] = h0 + h1;
        wbase[3][i] = h0 + h1 + h2;
        tot[i] = h0 + h1 + h2 + h3;
    }
    __syncthreads();
    // exclusive scan of tot over 352 bins (2 bins per thread, t<176)
    int v0 = (t < NB_BKT / 2) ? tot[2 * t] : 0;
    int v1 = (t < NB_BKT / 2) ? tot[2 * t + 1] : 0;
    int s = v0 + v1;
    scn[t] = s;
    __syncthreads();
    for (int st = 1; st < 256; st <<= 1) {
        int u = (t >= st) ? scn[t - st] : 0;
        __syncthreads();
        scn[t] += u;
        __syncthreads();
    }
    int base = scn[t] - s;
    if (t < NB_BKT / 2) {
        excl[2 * t] = base;
        excl[2 * t + 1] = base + v0;
    }
    __syncthreads();
    // finalize per-wave bases; reset histw for reuse as placement cursors
    for (int i = t; i < NB_BKT; i += 256) {
        int e0 = excl[i];
        wbase[0][i] += e0;
        wbase[1][i] += e0;
        wbase[2][i] += e0;
        wbase[3][i] += e0;
        histw[0][i] = 0; histw[1][i] = 0; histw[2][i] = 0; histw[3][i] = 0;
    }
    __syncthreads();
    // place into LDS tile buffer (bucket-contiguous; per-wave cursor)
#pragma unroll
    for (int q = 0; q < 8; q++) {
        if (myk[q] >= 0) {
            int b = myk[q] >> BKT_SH;
            int p = wbase[w][b] + atomicAdd(&histw[w][b], 1);
            tbuf[p] = make_int2(myk[q], mys[q]);
        }
    }
    __syncthreads();
    // reserve global runs
    for (int i = t; i < NB_BKT; i += 256)
        if (tot[i] > 0) gbase[i] = atomicAdd(&gcur[i], tot[i]);
    __syncthreads();
    // flush: consecutive i -> mostly consecutive global positions
    for (int i = t; i < tcount; i += 256) {
        int2 p = tbuf[i];
        int b = p.x >> BKT_SH;
        int gpos = gbase[b] + (i - excl[b]);
        int cap = (b + 1) * BKT_CAP - 1;
        pairs[gpos < cap ? gpos : cap] = p;
    }
}

// ---------------------------------------------------------------------------
// Pass B (merged hist+place): per-(key,src-group) histogram + block scan ->
// off/endo/inv, then place into CSR with src-group-major order per key.
// 352 blocks (512 keys each). LDS: kh[512*NG] = 16 KB.
__global__ void __launch_bounds__(256) histplace_kernel(
        const int* __restrict__ gcur, const int2* __restrict__ pairs,
        int* __restrict__ off, int* __restrict__ endo, float* __restrict__ inv,
        int* __restrict__ csr) {
    __shared__ int kh[512 * NG];
    __shared__ int scn[256];
    int b = blockIdx.x;
    int t = threadIdx.x;
    int beg = b * BKT_CAP, end = gcur[b];
    for (int i = t; i < 512 * NG; i += 256) kh[i] = 0;
    __syncthreads();
    for (int i = beg + t; i < end; i += 256) {
        int2 p = pairs[i];
        atomicAdd(&kh[(p.x & 511) * NG + (p.y >> 14)], 1);
    }
    __syncthreads();
    int cnt[2][NG];
    int v[2];
    int s = 0;
#pragma unroll
    for (int q = 0; q < 2; q++) {
        int key = t * 2 + q;
        v[q] = 0;
#pragma unroll
        for (int g = 0; g < NG; g++) {
            cnt[q][g] = kh[key * NG + g];
            v[q] += cnt[q][g];
        }
        s += v[q];
    }
    scn[t] = s;
    __syncthreads();
    for (int st = 1; st < 256; st <<= 1) {
        int u = (t >= st) ? scn[t - st] : 0;
        __syncthreads();
        scn[t] += u;
        __syncthreads();
    }
    int run = beg + scn[t] - s;
    int kbase = b << BKT_SH;
#pragma unroll
    for (int q = 0; q < 2; q++) {
        int key = kbase + t * 2 + q;
        if (key < TWO_NN) {
            off[key] = run;
            endo[key] = run + v[q];
            inv[key] = 1.0f / (float)(v[q] > 1 ? v[q] : 1);
        }
        // group-major cursor bases within this key's run (owned slots)
        int gb = run;
#pragma unroll
        for (int g = 0; g < NG; g++) {
            kh[(t * 2 + q) * NG + g] = gb;
            gb += cnt[q][g];
        }
        run += v[q];
    }
    __syncthreads();
    for (int i = beg + t; i < end; i += 256) {
        int2 p = pairs[i];
        int pos = atomicAdd(&kh[(p.x & 511) * NG + (p.y >> 14)], 1);
        csr[pos] = p.y;
    }
}

// ---------------------------------------------------------------------------
// Fused input embed (paper+mesh): writes bf16 activations only.
__global__ void __launch_bounds__(256) embed2_kernel(
        const float* __restrict__ Xp, const float* __restrict__ Xm,
        const float* __restrict__ Wp, const float* __restrict__ bp,
        const float* __restrict__ Wm, const float* __restrict__ bm,
        unsigned short* __restrict__ outbf) {
    __shared__ float Wl[4096 + 32];
    for (int i = threadIdx.x; i < 2048; i += 256) {
        Wl[i] = Wp[i];
        Wl[2048 + i] = Wm[i];
    }
    if (threadIdx.x < 16) {
        Wl[4096 + threadIdx.x] = bp[threadIdx.x];
        Wl[4112 + threadIdx.x] = bm[threadIdx.x];
    }
    __syncthreads();
    int n = blockIdx.x * 256 + threadIdx.x;
    if (n >= NN) return;
    const float* X;
    const float* Ws;
    const float* Bs;
    if (n < NP) { X = Xp + (size_t)n * 128; Ws = Wl; Bs = Wl + 4096; }
    else        { X = Xm + (size_t)(n - NP) * 128; Ws = Wl + 2048; Bs = Wl + 4112; }
    float acc[16];
#pragma unroll
    for (int j = 0; j < 16; j++) acc[j] = Bs[j];
    const float4* row = (const float4*)X;
    for (int k4 = 0; k4 < 32; k4++) {
        float4 xv = row[k4];
        int k = k4 * 4;
#pragma unroll
        for (int j = 0; j < 16; j++) {
            float a = acc[j];
            a = fmaf(xv.x, Ws[(k + 0) * 16 + j], a);
            a = fmaf(xv.y, Ws[(k + 1) * 16 + j], a);
            a = fmaf(xv.z, Ws[(k + 2) * 16 + j], a);
            a = fmaf(xv.w, Ws[(k + 3) * 16 + j], a);
            acc[j] = a;
        }
    }
    ushort4* ob = (ushort4*)(outbf + (size_t)n * 16);
#pragma unroll
    for (int q = 0; q < 4; q++) {
        ushort4 ub;
        ub.x = f2bf(acc[4 * q]);     ub.y = f2bf(acc[4 * q + 1]);
        ub.z = f2bf(acc[4 * q + 2]); ub.w = f2bf(acc[4 * q + 3]);
        ob[q] = ub;
    }
}

// ---------------------------------------------------------------------------
// All 4 layers' weight prep in ONE launch: block l handles layer l.
// Wbuf4 layout per layer (stride 3200): [W0 | W1 | root | bias]
__global__ void prep_all_kernel(
        const float* __restrict__ ba0, const float* __restrict__ co0,
        const float* __restrict__ ro0, const float* __restrict__ bi0,
        const float* __restrict__ ba1, const float* __restrict__ co1,
        const float* __restrict__ ro1, const float* __restrict__ bi1,
        const float* __restrict__ ba2, const float* __restrict__ co2,
        const float* __restrict__ ro2, const float* __restrict__ bi2,
        const float* __restrict__ ba3, const float* __restrict__ co3,
        const float* __restrict__ ro3, const float* __restrict__ bi3,
        float* __restrict__ Wbuf4) {
    int l = blockIdx.x;
    const float* bases; const float* comp; const float* root; const float* bias;
    if (l == 0)      { bases = ba0; comp = co0; root = ro0; bias = bi0; }
    else if (l == 1) { bases = ba1; comp = co1; root = ro1; bias = bi1; }
    else if (l == 2) { bases = ba2; comp = co2; root = ro2; bias = bi2; }
    else             { bases = ba3; comp = co3; root = ro3; bias = bi3; }
    int din = (l == 0) ? 16 : 32;
    int dout = (l == 3) ? 16 : 32;
    int sz = din * dout;
    float* W = Wbuf4 + l * 3200;
    for (int i = threadIdx.x; i < sz; i += 256) {
        float b0 = bases[i];
        float b1 = bases[sz + i];
        float b2 = bases[2 * sz + i];
        float b3 = bases[3 * sz + i];
        for (int r = 0; r < 2; r++) {
            W[r * sz + i] = comp[r * 4 + 0] * b0 + comp[r * 4 + 1] * b1 +
                            comp[r * 4 + 2] * b2 + comp[r * 4 + 3] * b3;
        }
        W[2 * sz + i] = root[i];
    }
    if (threadIdx.x < dout) W[3 * sz + threadIdx.x] = bias[threadIdx.x];
}

// ---------------------------------------------------------------------------
// Fused RGCN layer, bf16-only activations. R18 structure (best known): 4-wide
// software-pipelined gather + 1-wide remainder; raw-bf16 xs tile.
// R20: input csr is src-group-ordered (see histplace) for L2 locality.
template <int DIN, int DOUT, int RELU>
__global__ void __launch_bounds__(256) layer_kernel(
        const int* __restrict__ off, const int* __restrict__ endo,
        const int* __restrict__ csr,
        const unsigned short* __restrict__ xbf_in,
        const float* __restrict__ inv, const float* __restrict__ Wbuf,
        unsigned short* __restrict__ xbf_out) {
    constexpr int SZ = DIN * DOUT;
    constexpr int QL = DIN / 8;       // gather lanes per (node, rel): 16 B each
    constexpr int TPN = 2 * QL;       // phase-1 threads per node
    constexpr int NPB = 256 / TPN;    // nodes per block
    constexpr int AGST = 2 * DIN + 4; // agg LDS row stride (floats)
    constexpr int XSST = DIN + 8;     // xs LDS row stride (ushorts, 16B-mult)
    __shared__ float Wl[3 * SZ + DOUT];
    __shared__ float agg[NPB * AGST];
    __shared__ unsigned short xsu[NPB * XSST];
    for (int i = threadIdx.x; i < 3 * SZ + DOUT; i += 256) Wl[i] = Wbuf[i];
    int t = threadIdx.x;
    int ln = t / TPN;
    int rl = t % TPN;
    int r = rl / QL;
    int lane = rl % QL;
    int d = blockIdx.x * NPB + ln;
    if (d < NN) {
        if (r == 0) {
            uint4 u = *(const uint4*)(xbf_in + (size_t)d * DIN + lane * 8);
            *(uint4*)&xsu[ln * XSST + lane * 8] = u; // raw bf16, unpack in ph2
        }
        int key = r * NN + d;
        int b = off[key];
        int e = endo[key];
        float a0[8] = {0, 0, 0, 0, 0, 0, 0, 0};
        float a1[8] = {0, 0, 0, 0, 0, 0, 0, 0};
        const unsigned short* hp = xbf_in + lane * 8;
        int k = b;
        if (k + 3 < e) {
            // software-pipelined 4-wide: indices for the current batch live in
            // s0..s3; next batch's csr loads issue while x-loads are in flight.
            int s0 = csr[k], s1 = csr[k + 1], s2 = csr[k + 2], s3 = csr[k + 3];
            k += 4;
            while (k + 3 < e) {
                uint4 u0 = *(const uint4*)(hp + (size_t)s0 * DIN);
                uint4 u1 = *(const uint4*)(hp + (size_t)s1 * DIN);
                uint4 u2 = *(const uint4*)(hp + (size_t)s2 * DIN);
                uint4 u3 = *(const uint4*)(hp + (size_t)s3 * DIN);
                s0 = csr[k]; s1 = csr[k + 1]; s2 = csr[k + 2]; s3 = csr[k + 3];
                k += 4;
                a0[0] += bflo(u0.x); a0[1] += bfhi(u0.x);
                a0[2] += bflo(u0.y); a0[3] += bfhi(u0.y);
                a0[4] += bflo(u0.z); a0[5] += bfhi(u0.z);
                a0[6] += bflo(u0.w); a0[7] += bfhi(u0.w);
                a1[0] += bflo(u1.x); a1[1] += bfhi(u1.x);
                a1[2] += bflo(u1.y); a1[3] += bfhi(u1.y);
                a1[4] += bflo(u1.z); a1[5] += bfhi(u1.z);
                a1[6] += bflo(u1.w); a1[7] += bfhi(u1.w);
                a0[0] += bflo(u2.x); a0[1] += bfhi(u2.x);
                a0[2] += bflo(u2.y); a0[3] += bfhi(u2.y);
                a0[4] += bflo(u2.z); a0[5] += bfhi(u2.z);
                a0[6] += bflo(u2.w); a0[7] += bfhi(u2.w);
                a1[0] += bflo(u3.x); a1[1] += bfhi(u3.x);
                a1[2] += bflo(u3.y); a1[3] += bfhi(u3.y);
                a1[4] += bflo(u3.z); a1[5] += bfhi(u3.z);
                a1[6] += bflo(u3.w); a1[7] += bfhi(u3.w);
            }
            // drain the in-flight batch
            uint4 u0 = *(const uint4*)(hp + (size_t)s0 * DIN);
            uint4 u1 = *(const uint4*)(hp + (size_t)s1 * DIN);
            uint4 u2 = *(const uint4*)(hp + (size_t)s2 * DIN);
            uint4 u3 = *(const uint4*)(hp + (size_t)s3 * DIN);
            a0[0] += bflo(u0.x); a0[1] += bfhi(u0.x);
            a0[2] += bflo(u0.y); a0[3] += bfhi(u0.y);
            a0[4] += bflo(u0.z); a0[5] += bfhi(u0.z);
            a0[6] += bflo(u0.w); a0[7] += bfhi(u0.w);
            a1[0] += bflo(u1.x); a1[1] += bfhi(u1.x);
            a1[2] += bflo(u1.y); a1[3] += bfhi(u1.y);
            a1[4] += bflo(u1.z); a1[5] += bfhi(u1.z);
            a1[6] += bflo(u1.w); a1[7] += bfhi(u1.w);
            a0[0] += bflo(u2.x); a0[1] += bfhi(u2.x);
            a0[2] += bflo(u2.y); a0[3] += bfhi(u2.y);
            a0[4] += bflo(u2.z); a0[5] += bfhi(u2.z);
            a0[6] += bflo(u2.w); a0[7] += bfhi(u2.w);
            a1[0] += bflo(u3.x); a1[1] += bfhi(u3.x);
            a1[2] += bflo(u3.y); a1[3] += bfhi(u3.y);
            a1[4] += bflo(u3.z); a1[5] += bfhi(u3.z);
            a1[6] += bflo(u3.w); a1[7] += bfhi(u3.w);
        }
        // remainder (<= 3)
        for (; k < e; k++) {
            uint4 u0 = *(const uint4*)(hp + (size_t)csr[k] * DIN);
            a0[0] += bflo(u0.x); a0[1] += bfhi(u0.x);
            a0[2] += bflo(u0.y); a0[3] += bfhi(u0.y);
            a0[4] += bflo(u0.z); a0[5] += bfhi(u0.z);
            a0[6] += bflo(u0.w); a0[7] += bfhi(u0.w);
        }
        float* ap = agg + ln * AGST + r * DIN + lane * 8;
        *(float4*)ap = make_float4(a0[0] + a1[0], a0[1] + a1[1],
                                   a0[2] + a1[2], a0[3] + a1[3]);
        *(float4*)(ap + 4) = make_float4(a0[4] + a1[4], a0[5] + a1[5],
                                         a0[6] + a1[6], a0[7] + a1[7]);
    }
    __syncthreads();
    constexpr int CPN = DOUT / 4;
    for (int tt = t; tt < NPB * CPN; tt += 256) {
        int ln2 = tt / CPN;
        int j0 = (tt % CPN) * 4;
        int d2 = blockIdx.x * NPB + ln2;
        if (d2 < NN) {
            float iv0 = inv[d2], iv1 = inv[NN + d2];
            float acc[4];
#pragma unroll
            for (int jj = 0; jj < 4; jj++) acc[jj] = Wl[3 * SZ + j0 + jj];
#pragma unroll
            for (int k2 = 0; k2 < DIN; k2 += 2) {
                unsigned up = *(const unsigned*)&xsu[ln2 * XSST + k2];
                float xv0 = bflo(up);
                float xv1 = bfhi(up);
                float m00 = agg[ln2 * AGST + k2] * iv0;
                float m10 = agg[ln2 * AGST + DIN + k2] * iv1;
                float m01 = agg[ln2 * AGST + k2 + 1] * iv0;
                float m11 = agg[ln2 * AGST + DIN + k2 + 1] * iv1;
                const float* w0a = &Wl[k2 * DOUT + j0];
                const float* w1a = &Wl[SZ + k2 * DOUT + j0];
                const float* wra = &Wl[2 * SZ + k2 * DOUT + j0];
#pragma unroll
                for (int jj = 0; jj < 4; jj++) {
                    acc[jj] = fmaf(xv0, wra[jj], acc[jj]);
                    acc[jj] = fmaf(m00, w0a[jj], acc[jj]);
                    acc[jj] = fmaf(m10, w1a[jj], acc[jj]);
                    acc[jj] = fmaf(xv1, wra[DOUT + jj], acc[jj]);
                    acc[jj] = fmaf(m01, w0a[DOUT + jj], acc[jj]);
                    acc[jj] = fmaf(m11, w1a[DOUT + jj], acc[jj]);
                }
            }
            if (RELU) {
#pragma unroll
                for (int jj = 0; jj < 4; jj++) acc[jj] = fmaxf(acc[jj], 0.0f);
            }
            ushort4 ub;
            ub.x = f2bf(acc[0]); ub.y = f2bf(acc[1]);
            ub.z = f2bf(acc[2]); ub.w = f2bf(acc[3]);
            *(ushort4*)(xbf_out + (size_t)d2 * DOUT + j0) = ub;
        }
    }
}

// ---------------------------------------------------------------------------
// Fused decode on bf16 z: out[i] = dot( z[s]@Wd_r + bd_r , z[d] ).
__global__ void __launch_bounds__(256) decode_fused_kernel(
        const unsigned short* __restrict__ zbf,
        const float* __restrict__ Wd0, const float* __restrict__ bd0,
        const float* __restrict__ Wd1, const float* __restrict__ bd1,
        const int* __restrict__ pei, const int* __restrict__ pet,
        const int* __restrict__ nei, const int* __restrict__ net_,
        float* __restrict__ out, const int* __restrict__ dflag) {
    __shared__ float W[2][256];
    __shared__ float B[2][16];
    for (int i = threadIdx.x; i < 256; i += 256) {
        W[0][i] = Wd0[i];
        W[1][i] = Wd1[i];
    }
    if (threadIdx.x < 16) {
        B[0][threadIdx.x] = bd0[threadIdx.x];
        B[1][threadIdx.x] = bd1[threadIdx.x];
    }
    __syncthreads();
    int i = blockIdx.x * 256 + threadIdx.x;
    if (i >= 2 * ED) return;
    int sft = dflag[0];
    const int* ei;
    const int* et;
    int e;
    if (i < ED) { ei = pei; et = pet; e = i; }
    else        { ei = nei; et = net_; e = i - ED; }
    int s = ei[(size_t)e << sft];
    int d = ei[(size_t)(ED + e) << sft];
    int r = et[(size_t)e << sft];
    float zs[16], zd[16];
    const uint4* sp = (const uint4*)(zbf + ((size_t)s << 4));
    const uint4* dp = (const uint4*)(zbf + ((size_t)d << 4));
#pragma unroll
    for (int h = 0; h < 2; h++) {
        uint4 us = sp[h];
        uint4 ud = dp[h];
        int o8 = h * 8;
        zs[o8 + 0] = bflo(us.x); zs[o8 + 1] = bfhi(us.x);
        zs[o8 + 2] = bflo(us.y); zs[o8 + 3] = bfhi(us.y);
        zs[o8 + 4] = bflo(us.z); zs[o8 + 5] = bfhi(us.z);
        zs[o8 + 6] = bflo(us.w); zs[o8 + 7] = bfhi(us.w);
        zd[o8 + 0] = bflo(ud.x); zd[o8 + 1] = bfhi(ud.x);
        zd[o8 + 2] = bflo(ud.y); zd[o8 + 3] = bfhi(ud.y);
        zd[o8 + 4] = bflo(ud.z); zd[o8 + 5] = bfhi(ud.z);
        zd[o8 + 6] = bflo(ud.w); zd[o8 + 7] = bfhi(ud.w);
    }
    const float* Wr = W[r];
    const float* Br = B[r];
    float acc = 0.0f;
#pragma unroll
    for (int j = 0; j < 16; j++) {
        float yj = Br[j];
#pragma unroll
        for (int k = 0; k < 16; k++) yj = fmaf(zs[k], Wr[k * 16 + j], yj);
        acc = fmaf(yj, zd[j], acc);
    }
    out[i] = acc;
}

// ---------------------------------------------------------------------------
extern "C" void kernel_launch(void* const* d_in, const int* in_sizes, int n_in,
                              void* d_out, int out_size, void* d_ws, size_t ws_size,
                              hipStream_t stream) {
    const float* x_paper = (const float*)d_in[0];
    const float* x_mesh  = (const float*)d_in[1];
    const int* tei  = (const int*)d_in[2];
    const int* tet  = (const int*)d_in[3];
    const int* pei  = (const int*)d_in[4];
    const int* pet  = (const int*)d_in[5];
    const int* nei  = (const int*)d_in[6];
    const int* net_ = (const int*)d_in[7];
    const float* Wp  = (const float*)d_in[8];
    const float* bp  = (const float*)d_in[9];
    const float* Wm  = (const float*)d_in[10];
    const float* bm  = (const float*)d_in[11];
    const float* Wd0 = (const float*)d_in[12];
    const float* bd0 = (const float*)d_in[13];
    const float* Wd1 = (const float*)d_in[14];
    const float* bd1 = (const float*)d_in[15];

    // Workspace carve-up (fp32/int32 elements) — ~42 MB total
    float* ws = (float*)d_ws;
    size_t o = 0;
    unsigned short* xbfA = (unsigned short*)(ws + o); o += (size_t)NN * 16;
    unsigned short* xbfB = (unsigned short*)(ws + o); o += (size_t)NN * 16;
    float* inv  = ws + o; o += (size_t)TWO_NN;
    int*   off  = (int*)(ws + o); o += (size_t)TWO_NN;
    int*   endo = (int*)(ws + o); o += (size_t)TWO_NN;
    int*   csr  = (int*)(ws + o); o += (size_t)NB_BKT * BKT_CAP; // padded (9 MB)
    int*   gcur = (int*)(ws + o); o += 512;
    int2*  pairs = (int2*)(ws + o); o += (size_t)2 * NB_BKT * BKT_CAP; // 18 MB
    float* Wbuf4 = ws + o; o += 4 * 3200;
    int*   dflag = (int*)(ws + o); o += 16;

    // 0. Init (gcur + dtype flag)
    init_kernel<<<(NB_BKT + 255) / 256, 256, 0, stream>>>(tei, gcur, dflag);

    // 1. Binned padded-bucket CSR build (once), src-group-ordered per key
    binA_kernel<<<N_TILES, 256, 0, stream>>>(tei, tet, dflag, gcur, pairs);
    histplace_kernel<<<NB_BKT, 256, 0, stream>>>(gcur, pairs, off, endo, inv, csr);

    // 2. Fused embed -> xbfA (bf16 only)
    embed2_kernel<<<(NN + 255) / 256, 256, 0, stream>>>(
        x_paper, x_mesh, Wp, bp, Wm, bm, xbfA);

    // 3. All layer weights in one launch
    prep_all_kernel<<<4, 256, 0, stream>>>(
        (const float*)d_in[16], (const float*)d_in[17], (const float*)d_in[18], (const float*)d_in[19],
        (const float*)d_in[20], (const float*)d_in[21], (const float*)d_in[22], (const float*)d_in[23],
        (const float*)d_in[24], (const float*)d_in[25], (const float*)d_in[26], (const float*)d_in[27],
        (const float*)d_in[28], (const float*)d_in[29], (const float*)d_in[30], (const float*)d_in[31],
        Wbuf4);

    // 4. Four fused RGCN layers, bf16 activations throughout
    int blk16 = (NN + 63) / 64; // DIN=16: NPB=64
    int blk32 = (NN + 31) / 32; // DIN=32: NPB=32
    layer_kernel<16, 32, 1><<<blk16, 256, 0, stream>>>(
        off, endo, csr, xbfA, inv, Wbuf4 + 0 * 3200, xbfB);
    layer_kernel<32, 32, 1><<<blk32, 256, 0, stream>>>(
        off, endo, csr, xbfB, inv, Wbuf4 + 1 * 3200, xbfA);
    layer_kernel<32, 32, 1><<<blk32, 256, 0, stream>>>(
        off, endo, csr, xbfA, inv, Wbuf4 + 2 * 3200, xbfB);
    layer_kernel<32, 16, 0><<<blk32, 256, 0, stream>>>(
        off, endo, csr, xbfB, inv, Wbuf4 + 3 * 3200, xbfA);
    // z (bf16) = xbfA [NN,16]

    // 5. Fused decode on bf16 z
    decode_fused_kernel<<<(2 * ED + 255) / 256, 256, 0, stream>>>(
        xbfA, Wd0, bd0, Wd1, bd1, pei, pet, nei, net_, (float*)d_out, dflag);
}